// Round 14
// baseline (142.424 us; speedup 1.0000x reference)
//
#include <hip/hip_runtime.h>

typedef __bf16 bf16x8 __attribute__((ext_vector_type(8)));
typedef float  f32x4  __attribute__((ext_vector_type(4)));

// Sizes: B=64, C=128, ORI=6, HW=784, NB=4, BS=32
// xh strides (floats): b:1204224, c:9408, ori:1568, hw:2, ri:1

static __device__ __forceinline__ unsigned short bf16bits(float f) {
  __bf16 h = (__bf16)f; return __builtin_bit_cast(unsigned short, h);
}
static __device__ __forceinline__ unsigned int pack2(float a, float b) {
  return (unsigned int)bf16bits(a) | ((unsigned int)bf16bits(b) << 16);
}

// ---------------- weight prep: combined real matrix, transposed [n][k], bf16,
// written as the PRE-SWIZZLED LDS image so the main kernel does a linear copy.
__global__ void prep_weights(const float* __restrict__ w1, const float* __restrict__ w2,
                             unsigned short* __restrict__ wg) {
  const int e = blockIdx.x * 256 + threadIdx.x;      // 0..32767
  const int nb    = e >> 13;
  const int layer = (e >> 12) & 1;
  const int n = (e >> 6) & 63;
  const int k = e & 63;
  const float* w = layer ? w2 : w1;
  const int kk = k & 31, nn = n & 31;
  float v;
  if (n < 32) {
    v = (k < 32) ?  w[((0 * 4 + nb) * 32 + kk) * 32 + nn]
                 : -w[((1 * 4 + nb) * 32 + kk) * 32 + nn];
  } else {
    v = (k < 32) ?  w[((1 * 4 + nb) * 32 + kk) * 32 + nn]
                 :  w[((0 * 4 + nb) * 32 + kk) * 32 + nn];
  }
  const int pos = nb * 8192 + layer * 4096 + n * 64 + (((k >> 3) ^ ((n >> 1) & 7)) * 8) + (k & 7);
  wg[pos] = bf16bits(v);
}

// ---------------- fused main kernel: 2-tile blocks, wave-private restage, 1 barrier total ----------------
// grid = 6272: bi < 4704 -> xh block (2 x 128-pos tiles); else lowpass (1568).
// XCD swizzle (4704 = 8*588): wgid = (bi&7)*588 + (bi>>3).
__global__ __launch_bounds__(256, 4)
void fused_kernel(const float* __restrict__ xh, const unsigned short* __restrict__ wg,
                  const float* __restrict__ b1, const float* __restrict__ b2,
                  const float* __restrict__ xl, const float* __restrict__ wll,
                  float* __restrict__ out) {
  __shared__ __align__(16) unsigned short Xs[128 * 64];   // X/H tile (bf16), wave-private quarters, 16KB
  __shared__ __align__(16) unsigned short Ws[2 * 64 * 64];// 16KB pre-swizzled weight image
  __shared__ __align__(16) float Bs[128];

  const int t = threadIdx.x;
  const int bi = blockIdx.x;

  if (bi >= 4704) {                       // ---- lowpass path: xl_out = xl * w_ll ----
    const int llb = bi - 4704;            // 0..1567, 1024 float4 each
    const float4* xi4 = reinterpret_cast<const float4*>(xl);
    const float4* w4  = reinterpret_cast<const float4*>(wll);
    float4* o4 = reinterpret_cast<float4*>(out);
#pragma unroll
    for (int j = 0; j < 4; ++j) {
      const int i = llb * 1024 + j * 256 + t;
      const float4 x = xi4[i];
      const float4 w = w4[i % 25088];
      float4 r; r.x = x.x * w.x; r.y = x.y * w.y; r.z = x.z * w.z; r.w = x.w * w.w;
      o4[i] = r;
    }
    return;
  }

  // bijective XCD-aware remap: consecutive tile-groups per XCD
  const int wgid = (bi & 7) * 588 + (bi >> 3);
  const int mtg = wgid % 196;                // group of 2 tiles (256 positions)
  const int snb = wgid / 196;
  const int ori = snb >> 2;
  const int nb  = snb & 3;
  const int p00 = mtg << 8;

  const int lane = t & 63;
  const int wv = t >> 6;
  const int lr = lane & 15;
  const int lg = lane >> 4;                  // channel-octet selector in staging, frag group in MFMA
  const int m  = lane & 15;                  // position-pair selector in staging

  char* XB = reinterpret_cast<char*>(Xs);
  const char* WB = reinterpret_cast<const char*>(Ws);
  const float* xb = xh + (size_t)(nb * 32) * 9408 + ori * 1568;
  float* ob = out + 6422528 + (size_t)(nb * 32) * 9408 + ori * 1568;

  f32x4 R[8];                                // staging regs, reused across tiles

  // wave-private staging: wave wv loads/packs ONLY rows [wv*32, wv*32+32)
  auto issueX = [&](int tb) {
    const int P = tb + wv * 32 + 2 * m;
    const int bb = P / 784;
    const int hw = P - bb * 784;             // even; P,P+1 share bb
    const float* s = xb + (size_t)bb * 1204224 + (size_t)(lg * 8) * 9408 + hw * 2;
#pragma unroll
    for (int j = 0; j < 8; ++j)
      R[j] = *reinterpret_cast<const f32x4*>(s + (size_t)j * 9408);  // re(p),im(p),re(p+1),im(p+1)
  };
  auto packX = [&]() {
    const int row = wv * 32 + 2 * m;
    const int s0 = (row >> 1) & 7;
    char* row0 = XB + row * 128;
    char* row1 = row0 + 128;
    uint4 u;
    u.x = pack2(R[0].x, R[1].x);  u.y = pack2(R[2].x, R[3].x);
    u.z = pack2(R[4].x, R[5].x);  u.w = pack2(R[6].x, R[7].x);
    *reinterpret_cast<uint4*>(row0 + ((lg ^ s0) * 16)) = u;            // row p, re
    u.x = pack2(R[0].y, R[1].y);  u.y = pack2(R[2].y, R[3].y);
    u.z = pack2(R[4].y, R[5].y);  u.w = pack2(R[6].y, R[7].y);
    *reinterpret_cast<uint4*>(row0 + (((lg + 4) ^ s0) * 16)) = u;      // row p, im
    u.x = pack2(R[0].z, R[1].z);  u.y = pack2(R[2].z, R[3].z);
    u.z = pack2(R[4].z, R[5].z);  u.w = pack2(R[6].z, R[7].z);
    *reinterpret_cast<uint4*>(row1 + ((lg ^ s0) * 16)) = u;            // row p+1, re
    u.x = pack2(R[0].w, R[1].w);  u.y = pack2(R[2].w, R[3].w);
    u.z = pack2(R[4].w, R[5].w);  u.w = pack2(R[6].w, R[7].w);
    *reinterpret_cast<uint4*>(row1 + (((lg + 4) ^ s0) * 16)) = u;      // row p+1, im
  };

  // ---- prologue: tile-0 X loads + W image + biases; the ONLY barrier ----
  issueX(p00);
  uint4 Wr[4];
  float Bv = 0.f;
  {
    const uint4* src = reinterpret_cast<const uint4*>(wg + nb * 8192);
#pragma unroll
    for (int it = 0; it < 4; ++it) Wr[it] = src[it * 256 + t];
  }
  if (t < 128) {
    const int layer = t >> 6, n = t & 63;
    const float* bsrc = layer ? b2 : b1;
    Bv = bsrc[((n >> 5) * 4 + nb) * 32 + (n & 31)];
  }
  __builtin_amdgcn_sched_barrier(0);
  {
    uint4* dst = reinterpret_cast<uint4*>(Ws);
#pragma unroll
    for (int it = 0; it < 4; ++it) dst[it * 256 + t] = Wr[it];
  }
  if (t < 128) Bs[t] = Bv;
  __syncthreads();                           // W/B visible; never sync again

#pragma unroll
  for (int tt = 0; tt < 2; ++tt) {
    const int p0t = p00 + tt * 128;

    packX();                                 // own rows only — no barrier needed
    if (tt == 0) issueX(p00 + 128);          // tile-1 loads fly under tile-0 compute
    __builtin_amdgcn_sched_barrier(0);       // pin loads/pack above compute

    // ---- layer 1: D1[n][p] = W1t * X^T (wave-private rows) ----
    f32x4 acc[4][2];
#pragma unroll
    for (int mi = 0; mi < 4; ++mi)
#pragma unroll
      for (int ni = 0; ni < 2; ++ni)
        acc[mi][ni] = (f32x4){0.f, 0.f, 0.f, 0.f};

#pragma unroll
    for (int ks = 0; ks < 2; ++ks) {
      bf16x8 wf[4], xf[2];
#pragma unroll
      for (int mi = 0; mi < 4; ++mi) {
        const int n = mi * 16 + lr;
        wf[mi] = *reinterpret_cast<const bf16x8*>(WB + n * 128 + (((ks * 4 + lg) ^ ((n >> 1) & 7)) * 16));
      }
#pragma unroll
      for (int ni = 0; ni < 2; ++ni) {
        const int p = wv * 32 + ni * 16 + lr;
        xf[ni] = *reinterpret_cast<const bf16x8*>(XB + p * 128 + (((ks * 4 + lg) ^ ((p >> 1) & 7)) * 16));
      }
#pragma unroll
      for (int mi = 0; mi < 4; ++mi)
#pragma unroll
        for (int ni = 0; ni < 2; ++ni)
          acc[mi][ni] = __builtin_amdgcn_mfma_f32_16x16x32_bf16(wf[mi], xf[ni], acc[mi][ni], 0, 0, 0);
    }

    // ---- ep1: H = relu(D1 + b1) -> own rows ----
#pragma unroll
    for (int mi = 0; mi < 4; ++mi) {
      const f32x4 bv = *reinterpret_cast<const f32x4*>(&Bs[mi * 16 + lg * 4]);
      const int gH = mi * 2 + (lg >> 1);
      const int offH = (lg & 1) * 8;
#pragma unroll
      for (int ni = 0; ni < 2; ++ni) {
        const int p = wv * 32 + ni * 16 + lr;
        const float h0 = fmaxf(acc[mi][ni][0] + bv[0], 0.f);
        const float h1 = fmaxf(acc[mi][ni][1] + bv[1], 0.f);
        const float h2 = fmaxf(acc[mi][ni][2] + bv[2], 0.f);
        const float h3 = fmaxf(acc[mi][ni][3] + bv[3], 0.f);
        uint2 u; u.x = pack2(h0, h1); u.y = pack2(h2, h3);
        *reinterpret_cast<uint2*>(XB + p * 128 + ((gH ^ ((p >> 1) & 7)) * 16) + offH) = u;
      }
    }

    // ---- layer 2: D2[n][p] = W2t * H^T (own rows) ----
    f32x4 acc2[4][2];
#pragma unroll
    for (int mi = 0; mi < 4; ++mi)
#pragma unroll
      for (int ni = 0; ni < 2; ++ni)
        acc2[mi][ni] = (f32x4){0.f, 0.f, 0.f, 0.f};

#pragma unroll
    for (int ks = 0; ks < 2; ++ks) {
      bf16x8 wf[4], hf[2];
#pragma unroll
      for (int mi = 0; mi < 4; ++mi) {
        const int n = mi * 16 + lr;
        wf[mi] = *reinterpret_cast<const bf16x8*>(WB + 8192 + n * 128 + (((ks * 4 + lg) ^ ((n >> 1) & 7)) * 16));
      }
#pragma unroll
      for (int ni = 0; ni < 2; ++ni) {
        const int p = wv * 32 + ni * 16 + lr;
        hf[ni] = *reinterpret_cast<const bf16x8*>(XB + p * 128 + (((ks * 4 + lg) ^ ((p >> 1) & 7)) * 16));
      }
#pragma unroll
      for (int mi = 0; mi < 4; ++mi)
#pragma unroll
        for (int ni = 0; ni < 2; ++ni)
          acc2[mi][ni] = __builtin_amdgcn_mfma_f32_16x16x32_bf16(wf[mi], hf[ni], acc2[mi][ni], 0, 0, 0);
    }

    // ---- ep2: out = D2 + b2, interleaved (re,im) float2 stores ----
#pragma unroll
    for (int ni = 0; ni < 2; ++ni) {
      const int p = wv * 32 + ni * 16 + lr;
      const int P = p0t + p;
      const int bb = P / 784;
      const int hw = P - bb * 784;
      float* obase = ob + (size_t)bb * 1204224 + hw * 2;
#pragma unroll
      for (int mi = 0; mi < 2; ++mi) {
        const f32x4 bre = *reinterpret_cast<const f32x4*>(&Bs[64 + mi * 16 + lg * 4]);
        const f32x4 bim = *reinterpret_cast<const f32x4*>(&Bs[64 + (mi + 2) * 16 + lg * 4]);
#pragma unroll
        for (int j = 0; j < 4; ++j) {
          const int c = mi * 16 + lg * 4 + j;
          float2 v;
          v.x = acc2[mi][ni][j] + bre[j];
          v.y = acc2[mi + 2][ni][j] + bim[j];
          *reinterpret_cast<float2*>(obase + (size_t)c * 9408) = v;
        }
      }
    }
  }
}

extern "C" void kernel_launch(void* const* d_in, const int* in_sizes, int n_in,
                              void* d_out, int out_size, void* d_ws, size_t ws_size,
                              hipStream_t stream) {
  (void)in_sizes; (void)n_in; (void)out_size; (void)ws_size;
  const float* xl  = (const float*)d_in[0];
  const float* xh  = (const float*)d_in[1];
  const float* wll = (const float*)d_in[2];
  const float* w1  = (const float*)d_in[3];
  const float* w2  = (const float*)d_in[4];
  const float* b1  = (const float*)d_in[5];
  const float* b2  = (const float*)d_in[6];
  float* out = (float*)d_out;
  unsigned short* wg = (unsigned short*)d_ws;   // 65536 bytes used

  prep_weights<<<128, 256, 0, stream>>>(w1, w2, wg);
  fused_kernel<<<6272, 256, 0, stream>>>(xh, wg, b1, b2, xl, wll, out);
}

// Round 16
// 129.255 us; speedup vs baseline: 1.1019x; 1.1019x over previous
//
#include <hip/hip_runtime.h>

typedef __bf16 bf16x8 __attribute__((ext_vector_type(8)));
typedef float  f32x4  __attribute__((ext_vector_type(4)));
typedef float  f32x2  __attribute__((ext_vector_type(2)));

// Sizes: B=64, C=128, ORI=6, HW=784, NB=4, BS=32
// xh strides (floats): b:1204224, c:9408, ori:1568, hw:2, ri:1

static __device__ __forceinline__ unsigned short bf16bits(float f) {
  __bf16 h = (__bf16)f; return __builtin_bit_cast(unsigned short, h);
}
static __device__ __forceinline__ unsigned int pack2(float a, float b) {
  return (unsigned int)bf16bits(a) | ((unsigned int)bf16bits(b) << 16);
}

// ---------------- weight prep: combined real matrix, transposed [n][k], bf16,
// written as the PRE-SWIZZLED LDS image so the main kernel does a linear copy.
__global__ void prep_weights(const float* __restrict__ w1, const float* __restrict__ w2,
                             unsigned short* __restrict__ wg) {
  const int e = blockIdx.x * 256 + threadIdx.x;      // 0..32767
  const int nb    = e >> 13;
  const int layer = (e >> 12) & 1;
  const int n = (e >> 6) & 63;
  const int k = e & 63;
  const float* w = layer ? w2 : w1;
  const int kk = k & 31, nn = n & 31;
  float v;
  if (n < 32) {
    v = (k < 32) ?  w[((0 * 4 + nb) * 32 + kk) * 32 + nn]
                 : -w[((1 * 4 + nb) * 32 + kk) * 32 + nn];
  } else {
    v = (k < 32) ?  w[((1 * 4 + nb) * 32 + kk) * 32 + nn]
                 :  w[((0 * 4 + nb) * 32 + kk) * 32 + nn];
  }
  const int pos = nb * 8192 + layer * 4096 + n * 64 + (((k >> 3) ^ ((n >> 1) & 7)) * 8) + (k & 7);
  wg[pos] = bf16bits(v);
}

// ---------------- fused main kernel, 128-pos tiles, 4 blocks/CU, XCD-swizzled ----------------
// R13 structure + NON-TEMPORAL output stores (output is write-once: keep it out of
// L2/L3 so the Infinity Cache retains the READ working set across replays).
// grid = 10976: bi < 9408 -> xh block; else lowpass.
__global__ __launch_bounds__(256, 4)
void fused_kernel(const float* __restrict__ xh, const unsigned short* __restrict__ wg,
                  const float* __restrict__ b1, const float* __restrict__ b2,
                  const float* __restrict__ xl, const float* __restrict__ wll,
                  float* __restrict__ out) {
  __shared__ __align__(16) unsigned short Xs[128 * 64];   // X tile -> H tile (bf16), 16KB
  __shared__ __align__(16) unsigned short Ws[2 * 64 * 64];// 16KB pre-swizzled weight image
  __shared__ __align__(16) float Bs[128];

  const int t = threadIdx.x;
  const int bi = blockIdx.x;

  if (bi >= 9408) {                       // ---- lowpass path: xl_out = xl * w_ll ----
    const int llb = bi - 9408;            // 0..1567, 1024 float4 each
    const f32x4* xi4 = reinterpret_cast<const f32x4*>(xl);
    const f32x4* w4  = reinterpret_cast<const f32x4*>(wll);
    f32x4* o4 = reinterpret_cast<f32x4*>(out);
#pragma unroll
    for (int j = 0; j < 4; ++j) {
      const int i = llb * 1024 + j * 256 + t;
      const f32x4 x = xi4[i];
      const f32x4 w = w4[i % 25088];
      const f32x4 r = x * w;
      __builtin_nontemporal_store(r, &o4[i]);
    }
    return;
  }

  // bijective XCD-aware remap: consecutive work per XCD
  const int wgid = (bi & 7) * 1176 + (bi >> 3);
  const int mt  = wgid % 392;
  const int snb = wgid / 392;
  const int ori = snb >> 2;
  const int nb  = snb & 3;
  const int p0 = mt << 7;                    // 128 positions per tile

  char* XB = reinterpret_cast<char*>(Xs);
  const char* WB = reinterpret_cast<const char*>(Ws);
  const float* xb = xh + (size_t)(nb * 32) * 9408 + ori * 1568;
  float* ob = out + 6422528 + (size_t)(nb * 32) * 9408 + ori * 1568;

  // ================= ISSUE PHASE: all global loads batched, no LDS writes =================
  // thread t: position pair p=2*(t&63),p+1; channels (t>>6)*8 .. +7
  // each wave load instruction = 64 lanes x 16B = 1KB contiguous segment
  f32x4 R[8];
  const int pp = t & 63;
  const int cb = (t >> 6) * 8;               // wave-constant channel base
  {
    const int P = p0 + 2 * pp;
    const int bb = P / 784;
    const int hw = P - bb * 784;             // even; P,P+1 share bb
    const float* s = xb + (size_t)bb * 1204224 + (size_t)cb * 9408 + hw * 2;
#pragma unroll
    for (int j = 0; j < 8; ++j)
      R[j] = *reinterpret_cast<const f32x4*>(s + (size_t)j * 9408);  // re(p),im(p),re(p+1),im(p+1)
  }
  uint4 Wr[4];                               // weight image chunks
  float Bv = 0.f;
  {
    const uint4* src = reinterpret_cast<const uint4*>(wg + nb * 8192);
#pragma unroll
    for (int it = 0; it < 4; ++it) Wr[it] = src[it * 256 + t];
  }
  if (t < 128) {
    const int layer = t >> 6, n = t & 63;
    const float* bsrc = layer ? b2 : b1;
    Bv = bsrc[((n >> 5) * 4 + nb) * 32 + (n & 31)];
  }
  __builtin_amdgcn_sched_barrier(0);         // loads stay ABOVE all LDS writes

  // ================= DRAIN PHASE: convert + LDS writes =================
  {
    uint4* dst = reinterpret_cast<uint4*>(Ws);
#pragma unroll
    for (int it = 0; it < 4; ++it) dst[it * 256 + t] = Wr[it];
  }
  if (t < 128) Bs[t] = Bv;
  // pack rows p=2*pp, p+1: re -> group gr=cb/8, im -> gr+4; slot = g ^ s0, s0=pp&7
  {
    const int p = 2 * pp;
    const int s0 = pp & 7;
    const int gr = t >> 6;
    char* row0 = XB + p * 128;
    char* row1 = row0 + 128;
    uint4 u;
    u.x = pack2(R[0].x, R[1].x);  u.y = pack2(R[2].x, R[3].x);
    u.z = pack2(R[4].x, R[5].x);  u.w = pack2(R[6].x, R[7].x);
    *reinterpret_cast<uint4*>(row0 + ((gr ^ s0) * 16)) = u;            // row p, re
    u.x = pack2(R[0].y, R[1].y);  u.y = pack2(R[2].y, R[3].y);
    u.z = pack2(R[4].y, R[5].y);  u.w = pack2(R[6].y, R[7].y);
    *reinterpret_cast<uint4*>(row0 + (((gr + 4) ^ s0) * 16)) = u;      // row p, im
    u.x = pack2(R[0].z, R[1].z);  u.y = pack2(R[2].z, R[3].z);
    u.z = pack2(R[4].z, R[5].z);  u.w = pack2(R[6].z, R[7].z);
    *reinterpret_cast<uint4*>(row1 + ((gr ^ s0) * 16)) = u;            // row p+1, re
    u.x = pack2(R[0].w, R[1].w);  u.y = pack2(R[2].w, R[3].w);
    u.z = pack2(R[4].w, R[5].w);  u.w = pack2(R[6].w, R[7].w);
    *reinterpret_cast<uint4*>(row1 + (((gr + 4) ^ s0) * 16)) = u;      // row p+1, im
  }
  __syncthreads();

  const int lane = t & 63;
  const int wv = t >> 6;                     // wave owns positions [wv*32, wv*32+32)
  const int lr = lane & 15;
  const int lg = lane >> 4;

  // ---- layer 1: D1[n][p] = W1t * X^T ----
  f32x4 acc[4][2];
#pragma unroll
  for (int mi = 0; mi < 4; ++mi)
#pragma unroll
    for (int ni = 0; ni < 2; ++ni)
      acc[mi][ni] = (f32x4){0.f, 0.f, 0.f, 0.f};

#pragma unroll
  for (int ks = 0; ks < 2; ++ks) {
    bf16x8 wf[4], xf[2];
#pragma unroll
    for (int mi = 0; mi < 4; ++mi) {
      const int n = mi * 16 + lr;
      wf[mi] = *reinterpret_cast<const bf16x8*>(WB + n * 128 + (((ks * 4 + lg) ^ ((n >> 1) & 7)) * 16));
    }
#pragma unroll
    for (int ni = 0; ni < 2; ++ni) {
      const int p = wv * 32 + ni * 16 + lr;
      xf[ni] = *reinterpret_cast<const bf16x8*>(XB + p * 128 + (((ks * 4 + lg) ^ ((p >> 1) & 7)) * 16));
    }
#pragma unroll
    for (int mi = 0; mi < 4; ++mi)
#pragma unroll
      for (int ni = 0; ni < 2; ++ni)
        acc[mi][ni] = __builtin_amdgcn_mfma_f32_16x16x32_bf16(wf[mi], xf[ni], acc[mi][ni], 0, 0, 0);
  }

  // ---- ep1: H = relu(D1 + b1) -> back into Xs (wave-private rows, no barrier) ----
#pragma unroll
  for (int mi = 0; mi < 4; ++mi) {
    const f32x4 bv = *reinterpret_cast<const f32x4*>(&Bs[mi * 16 + lg * 4]);
    const int gH = mi * 2 + (lg >> 1);
    const int offH = (lg & 1) * 8;
#pragma unroll
    for (int ni = 0; ni < 2; ++ni) {
      const int p = wv * 32 + ni * 16 + lr;
      const float h0 = fmaxf(acc[mi][ni][0] + bv[0], 0.f);
      const float h1 = fmaxf(acc[mi][ni][1] + bv[1], 0.f);
      const float h2 = fmaxf(acc[mi][ni][2] + bv[2], 0.f);
      const float h3 = fmaxf(acc[mi][ni][3] + bv[3], 0.f);
      uint2 u; u.x = pack2(h0, h1); u.y = pack2(h2, h3);
      *reinterpret_cast<uint2*>(XB + p * 128 + ((gH ^ ((p >> 1) & 7)) * 16) + offH) = u;
    }
  }

  // ---- layer 2: D2[n][p] = W2t * H^T (wave-private rows) ----
  f32x4 acc2[4][2];
#pragma unroll
  for (int mi = 0; mi < 4; ++mi)
#pragma unroll
    for (int ni = 0; ni < 2; ++ni)
      acc2[mi][ni] = (f32x4){0.f, 0.f, 0.f, 0.f};

#pragma unroll
  for (int ks = 0; ks < 2; ++ks) {
    bf16x8 wf[4], hf[2];
#pragma unroll
    for (int mi = 0; mi < 4; ++mi) {
      const int n = mi * 16 + lr;
      wf[mi] = *reinterpret_cast<const bf16x8*>(WB + 8192 + n * 128 + (((ks * 4 + lg) ^ ((n >> 1) & 7)) * 16));
    }
#pragma unroll
    for (int ni = 0; ni < 2; ++ni) {
      const int p = wv * 32 + ni * 16 + lr;
      hf[ni] = *reinterpret_cast<const bf16x8*>(XB + p * 128 + (((ks * 4 + lg) ^ ((p >> 1) & 7)) * 16));
    }
#pragma unroll
    for (int mi = 0; mi < 4; ++mi)
#pragma unroll
      for (int ni = 0; ni < 2; ++ni)
        acc2[mi][ni] = __builtin_amdgcn_mfma_f32_16x16x32_bf16(wf[mi], hf[ni], acc2[mi][ni], 0, 0, 0);
  }

  // ---- ep2: out = D2 + b2, interleaved (re,im) NON-TEMPORAL f32x2 stores ----
#pragma unroll
  for (int ni = 0; ni < 2; ++ni) {
    const int p = wv * 32 + ni * 16 + lr;
    const int P = p0 + p;
    const int bb = P / 784;
    const int hw = P - bb * 784;
    float* obase = ob + (size_t)bb * 1204224 + hw * 2;
#pragma unroll
    for (int mi = 0; mi < 2; ++mi) {
      const f32x4 bre = *reinterpret_cast<const f32x4*>(&Bs[64 + mi * 16 + lg * 4]);
      const f32x4 bim = *reinterpret_cast<const f32x4*>(&Bs[64 + (mi + 2) * 16 + lg * 4]);
#pragma unroll
      for (int j = 0; j < 4; ++j) {
        const int c = mi * 16 + lg * 4 + j;
        f32x2 v;
        v[0] = acc2[mi][ni][j] + bre[j];
        v[1] = acc2[mi + 2][ni][j] + bim[j];
        __builtin_nontemporal_store(v, reinterpret_cast<f32x2*>(obase + (size_t)c * 9408));
      }
    }
  }
}

extern "C" void kernel_launch(void* const* d_in, const int* in_sizes, int n_in,
                              void* d_out, int out_size, void* d_ws, size_t ws_size,
                              hipStream_t stream) {
  (void)in_sizes; (void)n_in; (void)out_size; (void)ws_size;
  const float* xl  = (const float*)d_in[0];
  const float* xh  = (const float*)d_in[1];
  const float* wll = (const float*)d_in[2];
  const float* w1  = (const float*)d_in[3];
  const float* w2  = (const float*)d_in[4];
  const float* b1  = (const float*)d_in[5];
  const float* b2  = (const float*)d_in[6];
  float* out = (float*)d_out;
  unsigned short* wg = (unsigned short*)d_ws;   // 65536 bytes used

  prep_weights<<<128, 256, 0, stream>>>(w1, w2, wg);
  fused_kernel<<<10976, 256, 0, stream>>>(xh, wg, b1, b2, xl, wll, out);
}